// Round 9
// baseline (158.413 us; speedup 1.0000x reference)
//
#include <hip/hip_runtime.h>

#define IN_N   4096
#define OW     4084          // (4096 + 2*1 - 15) + 1
#define KS     15
#define TILE   64            // 64x64 output tile
#define XROWS  78            // TILE + 14 halo rows
#define XS     88            // LDS row stride in halfwords (176 B)
#define TPB    4             // stacked tiles per block
#define NBX    64
#define NBY    16
#define NRT    64            // total row tiles

typedef __attribute__((ext_vector_type(8))) short     v8s;   // raw 16B
typedef __attribute__((ext_vector_type(8))) _Float16  v8h;   // f16 A/B frag (4 VGPR)
typedef __attribute__((ext_vector_type(4))) float     v4f;   // C/D frag
typedef __attribute__((ext_vector_type(2))) float     v2f;
typedef __attribute__((ext_vector_type(2))) unsigned  v2u;

// ---- pre-kernel: build the 15 banded-B MFMA fragments once into d_ws ----
// B_ky[k][n] = w[ky, k-1-n] (band k ∈ [n+1, n+15]); A k-window starts at EVEN
// global col X0-2 -> aligned float2 staging.
// lane e holds B[k = (e>>4)*8 + j][n = e&15], j = 0..7  (16 B per lane)
__global__ void build_B(const float* __restrict__ w, unsigned short* __restrict__ Bg) {
    int ky = blockIdx.x;         // 15
    int e  = threadIdx.x;        // 64
    int n = e & 15, quad = e >> 4;
    unsigned short vals[8];
    #pragma unroll
    for (int j = 0; j < 8; ++j) {
        int d = quad * 8 + j - 1 - n;                 // shifted band
        _Float16 h = (_Float16)0.0f;
        if (d >= 0 && d < KS) h = (_Float16)w[ky * KS + d];   // RTNE f32->f16
        union { _Float16 hh; unsigned short u; } cv; cv.hh = h;
        vals[j] = cv.u;
    }
    *(v8s*)(&Bg[(ky * 64 + e) * 8]) = *(const v8s*)vals;
}

__device__ __forceinline__ unsigned pk(float a, float b) {
    return __builtin_bit_cast(unsigned, __builtin_amdgcn_cvt_pkrtz(a, b));
}

// R1's proven stage: 240 of 256 threads, 12 rows x 20 col-units, 7 sweeps.
__device__ __forceinline__ void stage_tile(
    const float* __restrict__ x, unsigned short* __restrict__ buf,
    int gtid, int R0, int X0, bool fast)
{
    if (gtid >= 240) return;
    const int tcol = gtid % 20;
    const int trow = gtid / 20;                   // 0..11
    const int c0 = 4 * tcol;                      // halfword col, 8B-aligned
    unsigned short* dst = &buf[trow * XS + c0];
    if (fast) {
        const float* xr = x + (size_t)(R0 - 1 + trow) * IN_N + (X0 - 2 + c0);
        #pragma unroll
        for (int i = 0; i < 7; ++i) {
            if (i < 6 || trow < 6) {              // rows 72..77 on last sweep
                v2f f01 = *(const v2f*)xr;        // aligned dwordx2
                v2f f23 = *(const v2f*)(xr + 2);
                v2u p;
                p.x = pk(f01.x, f01.y);
                p.y = pk(f23.x, f23.y);
                *(v2u*)dst = p;                   // ds_write_b64
            }
            xr  += 12 * (size_t)IN_N;
            dst += 12 * XS;
        }
    } else {
        const int gc0 = X0 - 2 + c0;
        #pragma unroll
        for (int i = 0; i < 7; ++i) {
            int row = trow + 12 * i;
            if (row < XROWS) {
                int gr = R0 - 1 + row;
                float f0 = 0.f, f1 = 0.f, f2 = 0.f, f3 = 0.f;
                if ((unsigned)gr < (unsigned)IN_N) {
                    const float* xr = x + (size_t)gr * IN_N;
                    if ((unsigned)(gc0 + 0) < (unsigned)IN_N) f0 = xr[gc0 + 0];
                    if ((unsigned)(gc0 + 1) < (unsigned)IN_N) f1 = xr[gc0 + 1];
                    if ((unsigned)(gc0 + 2) < (unsigned)IN_N) f2 = xr[gc0 + 2];
                    if ((unsigned)(gc0 + 3) < (unsigned)IN_N) f3 = xr[gc0 + 3];
                }
                v2u p;
                p.x = pk(f0, f1);
                p.y = pk(f2, f3);
                *(v2u*)(&buf[row * XS + c0]) = p;
            }
        }
    }
}

// R1's proven compute + store (4 waves of the group, rolling B prefetch).
__device__ __forceinline__ void compute_tile(
    const unsigned short* __restrict__ buf, const v8h* __restrict__ Bgv,
    float* __restrict__ out, float bv, int gtid, int R0, int X0, bool safe)
{
    const int lane = gtid & 63;
    const int wv   = gtid >> 6;
    const int m    = lane & 15;
    const int quad = lane >> 4;

    v4f acc[4];
    #pragma unroll
    for (int t = 0; t < 4; ++t) acc[t] = (v4f){0.f, 0.f, 0.f, 0.f};

    v8h bcur = Bgv[lane];                             // ky = 0 (LLC-resident)
    const unsigned short* arow = &buf[(wv * 16 + m) * XS + quad * 8];

    #pragma unroll
    for (int ky = 0; ky < KS; ++ky) {
        v8h bnext = (ky < KS - 1) ? Bgv[(ky + 1) * 64 + lane] : bcur;
        v8h a0 = *(const v8h*)(arow + 0);             // ds_read_b128 x4
        v8h a1 = *(const v8h*)(arow + 16);
        v8h a2 = *(const v8h*)(arow + 32);
        v8h a3 = *(const v8h*)(arow + 48);
        acc[0] = __builtin_amdgcn_mfma_f32_16x16x32_f16(a0, bcur, acc[0], 0, 0, 0);
        acc[1] = __builtin_amdgcn_mfma_f32_16x16x32_f16(a1, bcur, acc[1], 0, 0, 0);
        acc[2] = __builtin_amdgcn_mfma_f32_16x16x32_f16(a2, bcur, acc[2], 0, 0, 0);
        acc[3] = __builtin_amdgcn_mfma_f32_16x16x32_f16(a3, bcur, acc[3], 0, 0, 0);
        arow += XS;
        bcur = bnext;
    }

    const int orow0 = R0 + wv * 16 + quad * 4;
    const int ocol0 = X0 + m;
    if (safe) {
        float* o0 = &out[(size_t)orow0 * OW + ocol0];
        #pragma unroll
        for (int t = 0; t < 4; ++t) {
            #pragma unroll
            for (int r = 0; r < 4; ++r)
                o0[(size_t)r * OW + t * 16] = acc[t][r] + bv;
        }
    } else {
        #pragma unroll
        for (int t = 0; t < 4; ++t) {
            int oc = ocol0 + t * 16;
            if (oc < OW) {
                #pragma unroll
                for (int r = 0; r < 4; ++r) {
                    int orow = orow0 + r;
                    if (orow < OW)
                        out[(size_t)orow * OW + oc] = acc[t][r] + bv;
                }
            }
        }
    }
}

// Producer/consumer wave-group ping-pong: 2 groups x 256 threads, 4 tiles.
// Group g stages tile t (t≡g mod 2) in phase t, computes it in phase t+1.
// Steady state: one group VMEM-stages while the other DS+MFMA-computes.
__global__ __launch_bounds__(512, 8) void conv2d_mfma11(
    const float* __restrict__ x, const unsigned short* __restrict__ Bg,
    const float* __restrict__ bias, float* __restrict__ out)
{
    __shared__ unsigned short xt[2][XROWS * XS] __attribute__((aligned(16)));

    const int tid  = threadIdx.x;
    const int gtid = tid & 255;
    const int grp  = tid >> 8;                   // 0 or 1
    const int bx = blockIdx.x, by = blockIdx.y;
    const int X0  = bx * TILE;
    const int RT0 = by * TPB;
    const bool colInt = (bx >= 1) & (bx <= NBX - 2);
    const float bv = bias[0];
    const v8h* Bgv = (const v8h*)Bg;

    #pragma unroll 1
    for (int p = 0; p <= TPB; ++p) {
        if ((p < TPB) & ((p & 1) == grp)) {
            const int RT = RT0 + p;
            stage_tile(x, xt[p & 1], gtid, RT * TILE, X0,
                       colInt & (RT >= 1) & (RT <= NRT - 2));
        } else if ((p >= 1) & (((p - 1) & 1) == grp)) {
            const int RT = RT0 + p - 1;
            compute_tile(xt[(p - 1) & 1], Bgv, out, bv, gtid,
                         RT * TILE, X0,
                         (bx < NBX - 1) & (RT < NRT - 1));
        }
        __syncthreads();
    }
}

extern "C" void kernel_launch(void* const* d_in, const int* in_sizes, int n_in,
                              void* d_out, int out_size, void* d_ws, size_t ws_size,
                              hipStream_t stream) {
    const float* x    = (const float*)d_in[0];
    const float* w    = (const float*)d_in[1];
    const float* bias = (const float*)d_in[2];
    float* out        = (float*)d_out;
    unsigned short* Bg = (unsigned short*)d_ws;     // 15 KiB of scratch

    build_B<<<dim3(KS), dim3(64), 0, stream>>>(w, Bg);
    dim3 grid(NBX, NBY);
    conv2d_mfma11<<<grid, dim3(512), 0, stream>>>(x, Bg, bias, out);
}

// Round 10
// 138.705 us; speedup vs baseline: 1.1421x; 1.1421x over previous
//
#include <hip/hip_runtime.h>

#define IN_N   4096
#define OW     4084          // (4096 + 2*1 - 15) + 1
#define KS     15
#define TILE   64            // 64x64 output tile per block (4 waves x 16 rows)
#define XROWS  78            // TILE + KS - 1
#define XS     88            // LDS row stride in halfwords (176 B: 16B-mult)
#define OBS    20            // bounce row stride in dwords (16B-mult, bank-spread)
#define NBX    64
#define NBY    64

typedef __attribute__((ext_vector_type(8))) short     v8s;   // raw 16B
typedef __attribute__((ext_vector_type(8))) _Float16  v8h;   // f16 A/B frag (4 VGPR)
typedef __attribute__((ext_vector_type(4))) float     v4f;   // C/D frag
typedef __attribute__((ext_vector_type(2))) float     v2f;
typedef __attribute__((ext_vector_type(2))) unsigned  v2u;

// ---- pre-kernel: build the 15 banded-B MFMA fragments once into d_ws ----
// B_ky[k][n] = w[ky, k-1-n] (band k ∈ [n+1, n+15]); A k-window starts at EVEN
// global col X0-2 -> aligned float2 staging.
// lane e holds B[k = (e>>4)*8 + j][n = e&15], j = 0..7  (16 B per lane)
__global__ void build_B(const float* __restrict__ w, unsigned short* __restrict__ Bg) {
    int ky = blockIdx.x;         // 15
    int e  = threadIdx.x;        // 64
    int n = e & 15, quad = e >> 4;
    unsigned short vals[8];
    #pragma unroll
    for (int j = 0; j < 8; ++j) {
        int d = quad * 8 + j - 1 - n;                 // shifted band
        _Float16 h = (_Float16)0.0f;
        if (d >= 0 && d < KS) h = (_Float16)w[ky * KS + d];   // RTNE f32->f16
        union { _Float16 hh; unsigned short u; } cv; cv.hh = h;
        vals[j] = cv.u;
    }
    *(v8s*)(&Bg[(ky * 64 + e) * 8]) = *(const v8s*)vals;
}

__device__ __forceinline__ unsigned pk(float a, float b) {
    return __builtin_bit_cast(unsigned, __builtin_amdgcn_cvt_pkrtz(a, b));
}

// Proven convoy base + per-wave LDS-bounce epilogue (dwordx2 stores).
__global__ __launch_bounds__(256, 8) void conv2d_mfma12(
    const float* __restrict__ x, const unsigned short* __restrict__ Bg,
    const float* __restrict__ bias, float* __restrict__ out)
{
    __shared__ unsigned short xtile[XROWS * XS] __attribute__((aligned(16)));
    __shared__ float obounce[4][16 * OBS]       __attribute__((aligned(16)));

    const int tid = threadIdx.x;
    const int bx = blockIdx.x, by = blockIdx.y;
    const int X0 = bx * TILE;
    const int Y0 = by * TILE;
    const bool interior = (bx > 0) & (bx < NBX - 1) & (by > 0) & (by < NBY - 1);

    // ---- stage input tile fp32 -> f16 (unchanged from 51.4 µs best) ----
    if (tid < 240) {
        const int tcol = tid % 20;
        const int trow = tid / 20;                    // 0..11
        const int c0 = 4 * tcol;                      // halfword col, 8B-aligned
        unsigned short* dst = &xtile[trow * XS + c0];
        if (interior) {
            const float* xr = x + (size_t)(Y0 - 1 + trow) * IN_N + (X0 - 2 + c0);
            #pragma unroll
            for (int i = 0; i < 7; ++i) {
                if (i < 6 || trow < 6) {              // rows 72..77 on last sweep
                    v2f f01 = *(const v2f*)xr;        // aligned dwordx2
                    v2f f23 = *(const v2f*)(xr + 2);
                    v2u p;
                    p.x = pk(f01.x, f01.y);
                    p.y = pk(f23.x, f23.y);
                    *(v2u*)dst = p;                   // ds_write_b64
                }
                xr  += 12 * (size_t)IN_N;
                dst += 12 * XS;
            }
        } else {
            const int gc0 = X0 - 2 + c0;
            #pragma unroll
            for (int i = 0; i < 7; ++i) {
                int row = trow + 12 * i;
                if (row < XROWS) {
                    int gr = Y0 - 1 + row;
                    float f0 = 0.f, f1 = 0.f, f2 = 0.f, f3 = 0.f;
                    if ((unsigned)gr < (unsigned)IN_N) {
                        const float* xr = x + (size_t)gr * IN_N;
                        if ((unsigned)(gc0 + 0) < (unsigned)IN_N) f0 = xr[gc0 + 0];
                        if ((unsigned)(gc0 + 1) < (unsigned)IN_N) f1 = xr[gc0 + 1];
                        if ((unsigned)(gc0 + 2) < (unsigned)IN_N) f2 = xr[gc0 + 2];
                        if ((unsigned)(gc0 + 3) < (unsigned)IN_N) f3 = xr[gc0 + 3];
                    }
                    v2u p;
                    p.x = pk(f0, f1);
                    p.y = pk(f2, f3);
                    *(v2u*)(&xtile[row * XS + c0]) = p;
                }
            }
        }
    }
    __syncthreads();

    // ---- MFMA main loop (rolling B prefetch, unchanged) ----
    const int lane = tid & 63;
    const int wv   = tid >> 6;
    const int m    = lane & 15;
    const int quad = lane >> 4;

    v4f acc[4];
    #pragma unroll
    for (int t = 0; t < 4; ++t) acc[t] = (v4f){0.f, 0.f, 0.f, 0.f};

    const v8h* Bgv = (const v8h*)Bg;
    v8h bcur = Bgv[lane];                             // ky = 0 (L2-resident)
    const unsigned short* arow = &xtile[(wv * 16 + m) * XS + quad * 8];

    #pragma unroll
    for (int ky = 0; ky < KS; ++ky) {
        v8h bnext = (ky < KS - 1) ? Bgv[(ky + 1) * 64 + lane] : bcur;
        v8h a0 = *(const v8h*)(arow + 0);             // ds_read_b128 x4
        v8h a1 = *(const v8h*)(arow + 16);
        v8h a2 = *(const v8h*)(arow + 32);
        v8h a3 = *(const v8h*)(arow + 48);
        acc[0] = __builtin_amdgcn_mfma_f32_16x16x32_f16(a0, bcur, acc[0], 0, 0, 0);
        acc[1] = __builtin_amdgcn_mfma_f32_16x16x32_f16(a1, bcur, acc[1], 0, 0, 0);
        acc[2] = __builtin_amdgcn_mfma_f32_16x16x32_f16(a2, bcur, acc[2], 0, 0, 0);
        acc[3] = __builtin_amdgcn_mfma_f32_16x16x32_f16(a3, bcur, acc[3], 0, 0, 0);
        arow += XS;
        bcur = bnext;
    }

    // ---- epilogue ----
    // D[m,n] frag layout: row = quad*4 + r, col = m (+16t).
    const float bv = bias[0];
    if (interior | ((bx < NBX - 1) & (by < NBY - 1))) {
        // per-wave bounce: transpose 16x16 sub-tile per round t, then
        // each lane stores 2x dwordx2 of a contiguous output row segment.
        float* ob = &obounce[wv][0];
        const int l4 = lane >> 2;                 // row 0..15 within wave tile
        const int c4 = lane & 3;                  // 4-dword col group
        const int orow_base = Y0 + wv * 16;
        #pragma unroll
        for (int t = 0; t < 4; ++t) {
            #pragma unroll
            for (int r = 0; r < 4; ++r)
                ob[(quad * 4 + r) * OBS + m] = acc[t][r] + bv;   // 2-way banks
            // compiler inserts lgkmcnt wait (same-array dependency)
            v2f lo = *(const v2f*)&ob[l4 * OBS + c4 * 4];
            v2f hi = *(const v2f*)&ob[l4 * OBS + c4 * 4 + 2];
            float* orow = &out[(size_t)(orow_base + l4) * OW + X0 + t * 16 + c4 * 4];
            *(v2f*)orow       = lo;               // 8B-aligned dwordx2
            *((v2f*)orow + 1) = hi;
        }
    } else {
        const int orow0 = Y0 + wv * 16 + quad * 4;
        const int ocol0 = X0 + m;
        #pragma unroll
        for (int t = 0; t < 4; ++t) {
            int oc = ocol0 + t * 16;
            if (oc < OW) {
                #pragma unroll
                for (int r = 0; r < 4; ++r) {
                    int orow = orow0 + r;
                    if (orow < OW)
                        out[(size_t)orow * OW + oc] = acc[t][r] + bv;
                }
            }
        }
    }
}

extern "C" void kernel_launch(void* const* d_in, const int* in_sizes, int n_in,
                              void* d_out, int out_size, void* d_ws, size_t ws_size,
                              hipStream_t stream) {
    const float* x    = (const float*)d_in[0];
    const float* w    = (const float*)d_in[1];
    const float* bias = (const float*)d_in[2];
    float* out        = (float*)d_out;
    unsigned short* Bg = (unsigned short*)d_ws;     // 15 KiB of scratch

    build_B<<<dim3(KS), dim3(64), 0, stream>>>(w, Bg);
    dim3 grid(NBX, NBY);
    conv2d_mfma12<<<grid, dim3(256), 0, stream>>>(x, Bg, bias, out);
}